// Round 8
// baseline (1467.456 us; speedup 1.0000x reference)
//
#include <hip/hip_runtime.h>

#define NN 8192
#define ALPHA  0.4f
#define THETA1 0.24f   // alpha*(1-alpha)
#define SLABW  128
#define NSLAB  (NN / SLABW)            // 64
#define SLABSZ ((size_t)NN * SLABW)    // elems per slab block (1,048,576)

typedef float    f32x2 __attribute__((ext_vector_type(2)));
typedef float    f32x4 __attribute__((ext_vector_type(4)));
typedef unsigned u32x2 __attribute__((ext_vector_type(2)));

__device__ __forceinline__ unsigned short f2bf(float f) {
    unsigned u = __float_as_uint(f);
    u += 0x7fffu + ((u >> 16) & 1u);      // round-to-nearest-even
    return (unsigned short)(u >> 16);
}

// ------------------------------------------------- degree + row counts
__global__ __launch_bounds__(256) void deg_count_kernel(const int* __restrict__ row,
                                                        const int* __restrict__ col,
                                                        float* __restrict__ deg,
                                                        int* __restrict__ cnt, int E) {
    int e = blockIdx.x * 256 + threadIdx.x;
    if (e >= E) return;
    unsigned r = (unsigned)row[e], c = (unsigned)col[e];
    if (r < NN && c < NN) {
        atomicAdd(&deg[c], 1.0f);     // unweighted in-degree on col (reference semantics)
        atomicAdd(&cnt[r], 1);        // CSR row count
    }
}

// ------------------------------------------------- exclusive scan (8192, one block)
__global__ __launch_bounds__(256) void scan_kernel(const int* __restrict__ cnt,
                                                   int* __restrict__ rowptr,
                                                   int* __restrict__ cursor) {
    __shared__ int sums[257];
    int t = threadIdx.x;
    int base = t * 32;
    int s = 0;
    for (int j = 0; j < 32; ++j) s += cnt[base + j];
    sums[t] = s;
    __syncthreads();
    if (t == 0) {
        int run = 0;
        for (int i = 0; i < 256; ++i) { int x = sums[i]; sums[i] = run; run += x; }
        sums[256] = run;
    }
    __syncthreads();
    int run = sums[t];
    for (int j = 0; j < 32; ++j) {
        rowptr[base + j] = run;
        cursor[base + j] = run;
        run += cnt[base + j];
    }
    if (t == 255) rowptr[NN] = sums[256];
}

// ----------------- normalized values -> dense f32 A + packed CSR fill
// packed entry: bits 0-12 = col, bits 16-31 = bf16(value)
__global__ __launch_bounds__(256) void fill_kernel(const int* __restrict__ row,
                                                   const int* __restrict__ col,
                                                   const float* __restrict__ attr,
                                                   const float* __restrict__ deg,
                                                   int* __restrict__ cursor,
                                                   unsigned* __restrict__ epk,
                                                   float* __restrict__ Af, int E) {
    int e = blockIdx.x * 256 + threadIdx.x;
    if (e >= E) return;
    unsigned r = (unsigned)row[e], c = (unsigned)col[e];
    if (r < NN && c < NN) {
        float v = rsqrtf(deg[r]) * attr[e] * rsqrtf(deg[c]);
        atomicAdd(&Af[(size_t)r * NN + c], v);             // dense A (coalesce semantics)
        int pos = atomicAdd(&cursor[r], 1);
        epk[pos] = ((unsigned)f2bf(v) << 16) | c;
    }
}

// --------------------------- f32 row-major -> bf16 SLAB-MAJOR [64][8192][128]
__global__ __launch_bounds__(256) void convert_slab_kernel(const float* __restrict__ in,
                                                           unsigned short* __restrict__ out) {
    int r = blockIdx.x;
    int t = threadIdx.x;
    const float* rowp = in + (size_t)r * NN;
#pragma unroll
    for (int k = 0; k < 8; ++k) {
        int c = k * 1024 + t * 4;
        f32x4 v = __builtin_nontemporal_load((const f32x4*)&rowp[c]);
        unsigned lo = ((unsigned)f2bf(v.y) << 16) | (unsigned)f2bf(v.x);
        unsigned hi = ((unsigned)f2bf(v.w) << 16) | (unsigned)f2bf(v.z);
        u32x2 pk = {lo, hi};
        size_t o = (size_t)(c >> 7) * SLABSZ + (size_t)r * SLABW + (c & 127);
        __builtin_nontemporal_store(pk, (u32x2*)&out[o]);
    }
}

// ------------------------------------------------- SpMM: acc = A(sparse-row r) * S
// S SLAB-MAJOR (2 MB contiguous blocks), XCD-dedicated slabs (proven L2-resident, r7).
// DUAL-EDGE half-wave gather: lanes 0-31 gather edge i, lanes 32-63 edge i+1,
// 8 B/lane (4 cols). One dwordx2 VMEM covers two edges; __shfl_xor(32) merges halves.
// FINAL=0: OutBf = bf16(I + A + acc) = I + A + A^2   (slab-major; reads Abf)
// FINAL=1: P = THETA1*acc + ALPHA*I  where acc = A*(I+A+A^2) = A+A^2+A^3 (row-major f32)
template <int FINAL>
__global__ __launch_bounds__(256) void spmm_kernel(const int* __restrict__ rowptr,
                                                   const unsigned* __restrict__ epk,
                                                   const unsigned short* __restrict__ S,
                                                   unsigned short* __restrict__ OutBf,
                                                   float* __restrict__ P,
                                                   const unsigned short* __restrict__ Abf) {
    int lane = threadIdx.x & 63;
    int wave = threadIdx.x >> 6;
    unsigned bid   = blockIdx.x;
    unsigned xcd   = bid & 7u;
    unsigned local = bid >> 3;                   // [0, 16384)
    unsigned slab  = (xcd << 3) | (local >> 11); // [0, 64), 8 slabs per XCD
    unsigned rg    = local & 2047u;              // row group [0, 2048)
    int r  = (int)(rg * 4 + wave);
    int e0 = __builtin_amdgcn_readfirstlane(rowptr[r]);
    int e1 = __builtin_amdgcn_readfirstlane(rowptr[r + 1]);
    int hiHalf = lane >> 5;                      // 0 | 1
    int l32 = lane & 31;
    const char* Sb = (const char*)(S + (size_t)slab * SLABSZ) + (l32 << 3); // 8 B/lane
    float a0 = 0.f, a1 = 0.f, a2 = 0.f, a3 = 0.f;

#define GATHER(u) (*(const u32x2*)(Sb + (((size_t)((u) & 0x1fffu)) << 8)))
#define ACCUM4(g, u) { float vv = __uint_as_float((u) & 0xffff0000u);          \
    a0 = fmaf(vv, __uint_as_float((g).x << 16), a0);                           \
    a1 = fmaf(vv, __uint_as_float((g).x & 0xffff0000u), a1);                   \
    a2 = fmaf(vv, __uint_as_float((g).y << 16), a2);                           \
    a3 = fmaf(vv, __uint_as_float((g).y & 0xffff0000u), a3); }

    const unsigned* ep = epk + e0;
    int n = e1 - e0;
    int npair = n >> 1;
    int p = 0;
    for (; p + 8 <= npair; p += 8) {             // 8 pairs = 16 edges, 8 gathers in flight
        unsigned sel[8];
#pragma unroll
        for (int j = 0; j < 8; ++j) {
            u32x2 q = *(const u32x2*)&ep[2 * (p + j)];
            sel[j] = hiHalf ? q.y : q.x;
        }
        u32x2 g[8];
#pragma unroll
        for (int j = 0; j < 8; ++j) g[j] = GATHER(sel[j]);
#pragma unroll
        for (int j = 0; j < 8; ++j) ACCUM4(g[j], sel[j]);
    }
    for (; p < npair; ++p) {
        u32x2 q = *(const u32x2*)&ep[2 * p];
        unsigned s = hiHalf ? q.y : q.x;
        u32x2 g = GATHER(s);
        ACCUM4(g, s);
    }
    if (n & 1) {                                 // odd edge: hi half contributes +0
        unsigned u = ep[n - 1];
        unsigned s = hiHalf ? 0u : u;
        u32x2 g = GATHER(s);
        ACCUM4(g, s);
    }
#undef GATHER
#undef ACCUM4

    a0 += __shfl_xor(a0, 32);                    // merge even-edge/odd-edge halves
    a1 += __shfl_xor(a1, 32);
    a2 += __shfl_xor(a2, 32);
    a3 += __shfl_xor(a3, 32);
    if (hiHalf) return;

    int cloc = l32 << 2;                         // 4 cols per lane
    int gc   = (int)(slab << 7) + cloc;
    int d    = r - gc;
    size_t idx_sm = (size_t)slab * SLABSZ + (size_t)r * SLABW + cloc;
    if (FINAL) {
        float o0 = THETA1 * a0, o1 = THETA1 * a1, o2 = THETA1 * a2, o3 = THETA1 * a3;
        if (d == 0) o0 += ALPHA;
        else if (d == 1) o1 += ALPHA;
        else if (d == 2) o2 += ALPHA;
        else if (d == 3) o3 += ALPHA;
        f32x4 o = {o0, o1, o2, o3};
        __builtin_nontemporal_store(o, (f32x4*)(P + (size_t)r * NN + gc));
    } else {
        u32x2 ab = __builtin_nontemporal_load((const u32x2*)(Abf + idx_sm));
        float o0 = a0 + __uint_as_float(ab.x << 16);
        float o1 = a1 + __uint_as_float(ab.x & 0xffff0000u);
        float o2 = a2 + __uint_as_float(ab.y << 16);
        float o3 = a3 + __uint_as_float(ab.y & 0xffff0000u);
        if (d == 0) o0 += 1.0f;
        else if (d == 1) o1 += 1.0f;
        else if (d == 2) o2 += 1.0f;
        else if (d == 3) o3 += 1.0f;
        u32x2 pk = { (((unsigned)f2bf(o1)) << 16) | (unsigned)f2bf(o0),
                     (((unsigned)f2bf(o3)) << 16) | (unsigned)f2bf(o2) };
        __builtin_nontemporal_store(pk, (u32x2*)(OutBf + idx_sm));
    }
}

// ------------------------------------------------------------------ launch
extern "C" void kernel_launch(void* const* d_in, const int* in_sizes, int n_in,
                              void* d_out, int out_size, void* d_ws, size_t ws_size,
                              hipStream_t stream) {
    const float* attr = (const float*)d_in[1];
    const int*   eidx = (const int*)d_in[2];
    int E = in_sizes[1];
    const int* row = eidx;
    const int* col = eidx + E;

    const size_t MAT = (size_t)NN * NN;
    unsigned short* Abf  = (unsigned short*)d_ws;            // 128 MB, slab-major A
    unsigned short* S2bf = Abf + MAT;                        // 128 MB, slab-major I+A+A^2
    float*    deg    = (float*)(S2bf + MAT);                 // 32 KB
    int*      cnt    = (int*)(deg + NN);                     // 32 KB
    int*      rowptr = cnt + NN;                             // (NN+2)*4
    int*      cursor = rowptr + NN + 2;                      // 32 KB
    unsigned* epk    = (unsigned*)(cursor + NN);             // E*4 B

    size_t need = MAT * 2 * sizeof(unsigned short)
                + (size_t)(NN * 4 + 2) * sizeof(int)
                + (size_t)E * sizeof(unsigned);
    if (ws_size < need) return;

    float* Af = (float*)d_out;     // f32 A staging in d_out (dead after convert)
    float* P  = (float*)d_out;     // final output overwrites it

    hipMemsetAsync(d_out, 0, MAT * sizeof(float), stream);
    hipMemsetAsync(deg, 0, NN * sizeof(float), stream);
    hipMemsetAsync(cnt, 0, NN * sizeof(int), stream);

    int eb = (E + 255) / 256;
    deg_count_kernel<<<eb, 256, 0, stream>>>(row, col, deg, cnt, E);
    scan_kernel<<<1, 256, 0, stream>>>(cnt, rowptr, cursor);
    fill_kernel<<<eb, 256, 0, stream>>>(row, col, attr, deg, cursor, epk, Af, E);
    convert_slab_kernel<<<NN, 256, 0, stream>>>(Af, Abf);

    const int SPMM_BLOCKS = 2048 * 64;   // (NN/4 row groups) x 64 slabs
    // pass 1: S2 = I + A + A^2
    spmm_kernel<0><<<SPMM_BLOCKS, 256, 0, stream>>>(rowptr, epk, Abf, S2bf, nullptr, Abf);
    // pass 2: P = THETA1 * (A * S2) + ALPHA*I
    spmm_kernel<1><<<SPMM_BLOCKS, 256, 0, stream>>>(rowptr, epk, S2bf, nullptr, P, nullptr);
}